// Round 20
// baseline (109.428 us; speedup 1.0000x reference)
//
#include <hip/hip_runtime.h>
#include <hip/hip_bf16.h>

// Problem constants
constexpr int BATCH = 4096;
constexpr int IN    = 512;
constexpr int OUT   = 512;
constexpr int ORD   = 8;
constexpr int NK    = ORD + 1;        // 9
constexpr float FA  = 1.0f, FB = 1.0f;

// GEMM inner dim EXCLUDES k=0 (J0 == 1 -> bias term), KP = 4096
constexpr int KP     = IN * ORD;
constexpr int KS_TOT = KP / 32;                // 128 k-steps total

typedef __attribute__((ext_vector_type(8))) short short8;   // 8 bf16
typedef __attribute__((ext_vector_type(4))) float floatx4;  // MFMA C/D

#define AS1 __attribute__((address_space(1)))
#define AS3 __attribute__((address_space(3)))

__device__ __forceinline__ float bf16bits_to_f32(short s) {
    union { unsigned int u; float f; } cv;
    cv.u = ((unsigned int)(unsigned short)s) << 16;
    return cv.f;
}
__device__ __forceinline__ short f32_to_bf16bits(float f) {
    __hip_bfloat16 h = __float2bfloat16(f);
    return *(short*)&h;
}

// ---------------------------------------------------------------------------
// Kernel 1 (fused prep): unchanged (control).
// ---------------------------------------------------------------------------
__global__ __launch_bounds__(256) void prep(const float* __restrict__ x,
                                            const float* __restrict__ w,
                                            const float* __restrict__ coeff,
                                            short* __restrict__ A2,
                                            short* __restrict__ B2,
                                            float* __restrict__ bias) {
    const int bid  = blockIdx.x;
    const int tid  = threadIdx.x;
    const int lane = tid & 63;
    const int quad = lane >> 4;
    const int l15  = lane & 15;

    if (bid < 1024) {
        const int mt  = bid >> 2;
        const int sub = ((bid & 3) << 2) + (tid >> 6);   // 0..15
        const int b   = mt * 16 + l15;
        const int i0  = sub * 32 + quad * 8;
        const float* xr = x + (size_t)b * IN + i0;
        float t[8];
#pragma unroll
        for (int e = 0; e < 8; ++e) {
            float xc = fminf(fmaxf(xr[e], -9.0f), 9.0f);
            float ex = __expf(2.0f * xc);
            t[e] = (ex - 1.0f) / (ex + 1.0f);
        }
        float pp[8], pc[8];
#pragma unroll
        for (int e = 0; e < 8; ++e) {
            pp[e] = 1.0f;
            pc[e] = 0.5f * (FA + FB + 2.0f) * t[e] - 0.5f * (FA - FB);
        }
        {
            short8 v;
#pragma unroll
            for (int e = 0; e < 8; ++e) v[e] = f32_to_bf16bits(pc[e]);
            *(short8*)(A2 + (((size_t)mt * KS_TOT + sub) * 64 + lane) * 8) = v;
        }
#pragma unroll
        for (int n = 2; n <= ORD; ++n) {
            float fn = (float)n;
            float k1 = (2.f*fn+FA+FB)*(2.f*fn+FA+FB-1.f) / (2.f*fn*(fn+FA+FB));
            float k2 = (2.f*fn+FA+FB-1.f)*(FA*FA-FB*FB) /
                       (2.f*fn*(fn+FA+FB)*(2.f*fn+FA+FB-2.f));
            float k3 = (fn+FA-1.f)*(fn+FB-1.f)*(2.f*fn+FA+FB) /
                       (fn*(fn+FA+FB)*(2.f*fn+FA+FB-2.f));
            short8 v;
#pragma unroll
            for (int e = 0; e < 8; ++e) {
                float nx = (k1*t[e] + k2)*pc[e] - k3*pp[e];
                pp[e] = pc[e]; pc[e] = nx;
                v[e] = f32_to_bf16bits(nx);
            }
            const int ks = (n - 1) * 16 + sub;
            *(short8*)(A2 + (((size_t)mt * KS_TOT + ks) * 64 + lane) * 8) = v;
        }
    } else if (bid < 1152) {
        const int b2  = bid - 1024;
        const int nt  = b2 >> 2;
        const int sub = ((b2 & 3) << 2) + (tid >> 6);
        const int o   = nt * 16 + l15;
        const int i0  = sub * 32 + quad * 8;
        const float* wr = w + (size_t)o * IN + i0;
        float wv[8];
#pragma unroll
        for (int e = 0; e < 8; ++e) wv[e] = wr[e];
        const float* cf = coeff + ((size_t)o * IN + i0) * NK;
#pragma unroll
        for (int n = 1; n <= ORD; ++n) {
            short8 v;
#pragma unroll
            for (int e = 0; e < 8; ++e)
                v[e] = f32_to_bf16bits(cf[(size_t)e * NK + n] * wv[e]);
            const int ks = (n - 1) * 16 + sub;
            *(short8*)(B2 + (((size_t)nt * KS_TOT + ks) * 64 + lane) * 8) = v;
        }
    } else {
        const int bb = bid - 1152;
        const int o  = bb * 4 + (tid >> 6);
        const float* cf = coeff + (size_t)o * IN * NK;
        const float* wr = w + (size_t)o * IN;
        float acc = 0.0f;
#pragma unroll
        for (int r = 0; r < IN / 64; ++r) {
            int i = r * 64 + lane;
            acc = fmaf(cf[(size_t)i * NK], wr[i], acc);
        }
#pragma unroll
        for (int off = 32; off >= 1; off >>= 1)
            acc += __shfl_xor(acc, off, 64);
        if (lane == 0) bias[o] = acc;
    }
}

// ---------------------------------------------------------------------------
// Kernel 2: FULL-K GEMM v7 == v5 REVERT (fusion + 128x32 + 2 blocks/CU).
//
// r28 post-mortem: v6 (64x64 LDS-dedup) measured 2.48x fill-normalized vs
// v5's 2.33x -> REGRESSION. The 12cyc/ds_read_b128 LDS-pipe model is
// falsified (halving A-reads had to win if LDS were the wall). Ledger:
// v2 2.43, v3 2.44, v4 2.52 (1 blk/CU, real loss), v5 2.33 (best),
// v6 2.48. v5 vs field is ~4% -- near the noise band, so this round
// replicates v5 unchanged to confirm before building on it.
//
// v5: tile 128x32, grid (32,16) = 512 blocks = 2/CU (launch_bounds(256,2)).
// LDS 48KB = 3 buffers x 16KB (2-kstep batches), stage distance 2. Per
// wave: 4 m-frags x 1 n-frag; B 1 frag/kstep via L1, loaded 1 iter ahead
// into alternate reg set. End-of-iter vmcnt(10): leaves [st(t+2)(8), B(2)]
// in flight, forces st(t+1) resident. id%8 = bx%8 -> A-panel XCD locality.
// ---------------------------------------------------------------------------
__global__ __launch_bounds__(256, 2) void gemm_full(
        const short* __restrict__ A2,   // [256 mt][128 ks] x 1KB lines
        const short* __restrict__ B2,   // [32 nt][128 ks]  x 1KB lines
        const float* __restrict__ bias, // [512]
        float* __restrict__ out)        // [4096][512] f32
{
    // 3 buffers x 2 ksteps x 8 m-lines x 512 shorts = 48 KB
    __shared__ short sA[3 * 8192];

    const int tid  = threadIdx.x;
    const int lane = tid & 63;
    const int quad = lane >> 4;
    const int l15  = lane & 15;
    const int wave = tid >> 6;
    const int mw   = wave & 1;          // m half (64 rows)
    const int nw   = wave >> 1;         // n half (16 cols)
    const int bx = blockIdx.x;          // 0..31  (m-tiles of 128)
    const int by = blockIdx.y;          // 0..15  (n-tiles of 32)

    // B pointer: 1 n-frag per wave (nt = by*2 + nw)
    const short* pb = B2 + ((size_t)(by * 2 + nw) * KS_TOT * 64 + lane) * 8;

    const int wv = wave;
    const short* aBase = A2 + ((size_t)(bx * 8) * KS_TOT) * 512;

    // Stage one 2-kstep batch (16 lines of 1KB) into buffer BUF.
    // Line ll = c*4+wv; mt = ll&7, s = ll>>3. Buffer layout [s][mt].
#define STAGE2(BT, BUF)                                                      \
    _Pragma("unroll")                                                        \
    for (int c = 0; c < 4; ++c) {                                            \
        const int ll = c * 4 + wv;                                           \
        const int mt = ll & 7;                                               \
        const int s  = ll >> 3;                                              \
        __builtin_amdgcn_global_load_lds(                                    \
            (const AS1 unsigned int*)(aBase +                                \
                ((size_t)mt * KS_TOT + (BT) * 2 + s) * 512 + lane * 8),      \
            (AS3 unsigned int*)(sA + (BUF) * 8192 + (c * 256 + tid) * 8),    \
            16, 0, 0);                                                       \
    }

    // Load k-pair (K0, K0+1): 2 global loads (one frag each kstep).
#define BLOAD(S0, S1, K0)                                                    \
    {                                                                        \
        S0 = *(const short8*)(pb + (size_t)(K0) * 512);                      \
        S1 = *(const short8*)(pb + (size_t)((K0) + 1) * 512);                \
    }

    floatx4 acc[4];
#pragma unroll
    for (int i = 0; i < 4; ++i) acc[i] = (floatx4)0.0f;

#define ASTEP(BUFI, S, BSLOT)                                                \
    {                                                                        \
        short8 af[4];                                                        \
        _Pragma("unroll")                                                    \
        for (int i = 0; i < 4; ++i)                                          \
            af[i] = *(const short8*)(sA + (BUFI) * 8192 +                    \
                        (((S) * 8 + mw * 4 + i) * 64 + lane) * 8);           \
        __builtin_amdgcn_s_setprio(1);                                       \
        _Pragma("unroll")                                                    \
        for (int i = 0; i < 4; ++i)                                          \
            acc[i] = __builtin_amdgcn_mfma_f32_16x16x32_bf16(                \
                         af[i], BSLOT, acc[i], 0, 0, 0);                     \
        __builtin_amdgcn_s_setprio(0);                                       \
    }

    short8 bsA0, bsA1, bsB0, bsB1;

    // Prologue: stage batches 0,1; B k=0,1 into set A.
    STAGE2(0, 0)
    STAGE2(1, 1)
    BLOAD(bsA0, bsA1, 0)
    // FIFO: [st0(8)][st1(8)][B(2)] -> vmcnt(10) forces st0 only.
    asm volatile("s_waitcnt vmcnt(10)" ::: "memory");
    __builtin_amdgcn_s_barrier();

    // Iter t: consume batch t (k=2t,2t+1) from buf t%3 with set C; stage
    // batch t+2 into buf (t+2)%3; load B k=2t+2 into the other set.
#define ITERX(T, BUF, SBUF, C0, C1, N0, N1)                                  \
    STAGE2((T) + 2, SBUF)                                                    \
    BLOAD(N0, N1, 2 * (T) + 2)                                               \
    ASTEP(BUF, 0, C0) ASTEP(BUF, 1, C1)                                      \
    asm volatile("s_waitcnt vmcnt(10)" ::: "memory");                        \
    __builtin_amdgcn_s_barrier();

    // Steady state: t = 0..59 in groups of 6 (lcm of 3 buffers, 2 sets).
    for (int g = 0; g < 10; ++g) {
        const int t0 = g * 6;
        ITERX(t0,     0, 2, bsA0, bsA1, bsB0, bsB1)
        ITERX(t0 + 1, 1, 0, bsB0, bsB1, bsA0, bsA1)
        ITERX(t0 + 2, 2, 1, bsA0, bsA1, bsB0, bsB1)
        ITERX(t0 + 3, 0, 2, bsB0, bsB1, bsA0, bsA1)
        ITERX(t0 + 4, 1, 0, bsA0, bsA1, bsB0, bsB1)
        ITERX(t0 + 5, 2, 1, bsB0, bsB1, bsA0, bsA1)
    }
    // t = 60 (even: consume A, load B), t = 61 (stage batch 63 -> buf 0).
    ITERX(60, 0, 2, bsA0, bsA1, bsB0, bsB1)
    ITERX(61, 1, 0, bsB0, bsB1, bsA0, bsA1)
    // t = 62: consume A from buf 2; load last B pair; no stage.
    BLOAD(bsB0, bsB1, 126)
    ASTEP(2, 0, bsA0) ASTEP(2, 1, bsA1)
    // In flight: [st63(8) from t=61, B(2)] -> vmcnt(2) forces st63.
    asm volatile("s_waitcnt vmcnt(2)" ::: "memory");
    __builtin_amdgcn_s_barrier();
    // t = 63: consume B from buf 0.
    ASTEP(0, 0, bsB0) ASTEP(0, 1, bsB1)

#undef ITERX
#undef ASTEP
#undef BLOAD
#undef STAGE2

    // Epilogue: C/D layout col = lane&15, row = quad*4 + reg.
    // out[b,o] = acc + bias[o], float, direct.
    const int m0 = bx * 128, n0 = by * 32;
    const int c  = n0 + nw * 16 + l15;
    const float bj = bias[c];
#pragma unroll
    for (int i = 0; i < 4; ++i) {
        const int r0 = m0 + mw * 64 + i * 16 + quad * 4;
#pragma unroll
        for (int r = 0; r < 4; ++r)
            out[(size_t)(r0 + r) * OUT + c] = acc[i][r] + bj;
    }
}

// ---------------------------------------------------------------------------
extern "C" void kernel_launch(void* const* d_in, const int* in_sizes, int n_in,
                              void* d_out, int out_size, void* d_ws, size_t ws_size,
                              hipStream_t stream) {
    const float* x     = (const float*)d_in[0];   // [4096,512]
    const float* w     = (const float*)d_in[1];   // [512,512]
    const float* coeff = (const float*)d_in[2];   // [512,512,9]
    float* out = (float*)d_out;                   // [4096,512]

    // workspace layout (bytes)
    char* ws = (char*)d_ws;
    short* A2 = (short*)ws;                                  // 33,554,432 B
    char* p1c = ws + (size_t)BATCH * KP * 2;
    short* B2 = (short*)p1c;                                 //  4,194,304 B
    float* bias = (float*)(p1c + (size_t)OUT * KP * 2);      //      2,048 B

    prep<<<1280, 256, 0, stream>>>(x, w, coeff, A2, B2, bias);
    gemm_full<<<dim3(32, 16), 256, 0, stream>>>(A2, B2, bias, out);
}